// Round 3
// baseline (142.428 us; speedup 1.0000x reference)
//
#include <hip/hip_runtime.h>
#include <stdint.h>

// Problem: LTCCell  B=256, I=512, H=512. ALL tensors float32 (per reference),
// output float32. Round-1 NaN proved f32 inputs; round-2's 0.3525 absmax
// matched bf16-packed-into-f32-buffer corruption; threshold = 2% * max|ref|.
constexpr int NB = 256;
constexpr int NI = 512;
constexpr int NH = 512;

constexpr int TB    = 16;   // batches register-blocked per lane
constexpr int CHUNK = 32;   // reduction rows per chunk (per side)
constexpr int NS    = 16;   // chunks: 512/32
constexpr int HBLK  = 256;  // h columns per block (== blockDim.x)

__device__ __forceinline__ float fast_exp2(float x) {
#if __has_builtin(__builtin_amdgcn_exp2f)
    return __builtin_amdgcn_exp2f(x);
#else
    return exp2f(x);
#endif
}
__device__ __forceinline__ float fast_rcp(float x) {
#if __has_builtin(__builtin_amdgcn_rcpf)
    return __builtin_amdgcn_rcpf(x);
#else
    return 1.0f / x;
#endif
}

// Accumulation kernel: each block = (chunk s, batch tile, h half).
// 512 blocks x 256 threads = 2048 waves (2 waves/SIMD), lane <-> h column,
// 16 batches register-blocked per lane. Partial num/den combined via f32
// atomics into the f32 workspace.
__global__ __launch_bounds__(256, 2) void ltc_accum(
    const float* __restrict__ inputs,   // NB x NI
    const float* __restrict__ state,    // NB x NH
    const float* __restrict__ smu, const float* __restrict__ ssg,
    const float* __restrict__ sW,  const float* __restrict__ ser,
    const float* __restrict__ imu, const float* __restrict__ isg,
    const float* __restrict__ iW,  const float* __restrict__ ier,
    float* __restrict__ wsNum, float* __restrict__ wsDen)
{
    __shared__ float xs[CHUNK][TB];   // inputs chunk, [row][batch]
    __shared__ float ss[CHUNK][TB];   // state  chunk, [row][batch]

    const int bi    = blockIdx.x;
    const int s     = bi & (NS - 1);
    const int btile = (bi >> 4) & 15;
    const int hhalf = bi >> 8;
    const int b0 = btile * TB;
    const int h  = hhalf * HBLK + threadIdx.x;
    const int r0 = s * CHUNK;

    // Stage x/state chunk to LDS, [row][batch] layout.
    for (int k = threadIdx.x; k < CHUNK * TB; k += 256) {
        const int ii = k >> 4, bb = k & (TB - 1);
        xs[ii][bb] = inputs[(b0 + bb) * NI + r0 + ii];
        ss[ii][bb] = state [(b0 + bb) * NH + r0 + ii];
    }
    __syncthreads();

    float num[TB], den[TB];
#pragma unroll
    for (int bb = 0; bb < TB; ++bb) { num[bb] = 0.f; den[bb] = 0.f; }

    const float LOG2E = 1.44269504088896340736f;

    // sigmoid((x-mu)*sig) = 1/(1+exp2(c - x*a)), a = sig*log2e, c = mu*a
#pragma unroll 2
    for (int ii = 0; ii < CHUNK; ++ii) {
        const int p = (r0 + ii) * NH + h;          // coalesced across lanes
        const float mu = smu[p];
        const float a  = ssg[p] * LOG2E;
        const float W  = sW[p];
        const float We = W * ser[p];
        const float c  = mu * a;
#pragma unroll
        for (int bb = 0; bb < TB; ++bb) {
            const float u = c - xs[ii][bb] * a;    // v_fma
            const float e = fast_exp2(u);          // v_exp_f32
            const float r = fast_rcp(e + 1.0f);    // v_add + v_rcp_f32
            den[bb] += W  * r;                     // v_fma
            num[bb] += We * r;                     // v_fma
        }
    }
#pragma unroll 2
    for (int ii = 0; ii < CHUNK; ++ii) {
        const int p = (r0 + ii) * NH + h;
        const float mu = imu[p];
        const float a  = isg[p] * LOG2E;
        const float W  = iW[p];
        const float We = W * ier[p];
        const float c  = mu * a;
#pragma unroll
        for (int bb = 0; bb < TB; ++bb) {
            const float u = c - ss[ii][bb] * a;
            const float e = fast_exp2(u);
            const float r = fast_rcp(e + 1.0f);
            den[bb] += W  * r;
            num[bb] += We * r;
        }
    }

#pragma unroll
    for (int bb = 0; bb < TB; ++bb) {
        unsafeAtomicAdd(&wsNum[(b0 + bb) * NH + h], num[bb]);  // global_atomic_add_f32
        unsafeAtomicAdd(&wsDen[(b0 + bb) * NH + h], den[bb]);
    }
}

// Epilogue: one thread per (b,h). Cheap relative to accumulation.
__global__ __launch_bounds__(256) void ltc_epilogue(
    const float* __restrict__ state,
    const float* __restrict__ vleak, const float* __restrict__ gleak,
    const float* __restrict__ cm,
    const float* __restrict__ wsNum, const float* __restrict__ wsDen,
    float* __restrict__ out)
{
    const int t = blockIdx.x * 256 + threadIdx.x;  // < NB*NH
    const int h = t & (NH - 1);
    const float st = state[t];
    const float gl = gleak[h];
    const float vl = vleak[h];
    const float c  = cm[h];
    const float wnum = wsNum[t];
    const float wden = wsDen[t];
    const float eps = 1e-8f;
    const float G = gl + wden;
    const float tau = c / (G + eps);
    const float numerator = c * st + gl * vl + wnum;
    const float denominator = c + G;
    const float v_inf = numerator / (denominator + eps);
    const float next = v_inf + (st - v_inf) * expf(-0.1f / (tau + eps));
    out[t] = tanhf(next);
}

extern "C" void kernel_launch(void* const* d_in, const int* in_sizes, int n_in,
                              void* d_out, int out_size, void* d_ws, size_t ws_size,
                              hipStream_t stream) {
    const float* inputs = (const float*)d_in[0];
    const float* state  = (const float*)d_in[1];
    const float* smu    = (const float*)d_in[2];
    const float* ssg    = (const float*)d_in[3];
    const float* sW     = (const float*)d_in[4];
    const float* ser    = (const float*)d_in[5];
    const float* imu    = (const float*)d_in[6];
    const float* isg    = (const float*)d_in[7];
    const float* iW     = (const float*)d_in[8];
    const float* ier    = (const float*)d_in[9];
    const float* vleak  = (const float*)d_in[10];
    const float* gleak  = (const float*)d_in[11];
    const float* cm     = (const float*)d_in[12];

    float* wsNum = (float*)d_ws;
    float* wsDen = wsNum + NB * NH;

    // ws is re-poisoned (0xAA) before every timed launch -> zero it ourselves.
    hipMemsetAsync(d_ws, 0, 2ull * NB * NH * sizeof(float), stream);

    ltc_accum<<<dim3(NS * 16 * 2), dim3(256), 0, stream>>>(
        inputs, state, smu, ssg, sW, ser, imu, isg, iW, ier, wsNum, wsDen);
    ltc_epilogue<<<dim3(NB * NH / 256), dim3(256), 0, stream>>>(
        state, vleak, gleak, cm, wsNum, wsDen, (float*)d_out);
}

// Round 4
// 124.235 us; speedup vs baseline: 1.1464x; 1.1464x over previous
//
#include <hip/hip_runtime.h>
#include <stdint.h>

// Problem: LTCCell  B=256, I=512, H=512. ALL tensors float32, output float32.
// R3: passed, accum 68us, VGPR=36 (compiler starved chains of scratch regs ->
// serial exp/rcp chains), occupancy 20%, VALUBusy 35% -> latency-bound.
// R4: TB 16->8 (32 batch tiles, grid 1024 = 4 blocks/CU = 4 waves/SIMD) +
// explicit r[TB] stage array for 8 independent trans chains per wave.
constexpr int NB = 256;
constexpr int NI = 512;
constexpr int NH = 512;

constexpr int TB    = 8;    // batches register-blocked per lane
constexpr int NT    = 32;   // batch tiles: 256/8
constexpr int CHUNK = 32;   // reduction rows per chunk (per side)
constexpr int NS    = 16;   // chunks: 512/32
constexpr int HBLK  = 256;  // h columns per block (== blockDim.x)

__device__ __forceinline__ float fast_exp2(float x) {
#if __has_builtin(__builtin_amdgcn_exp2f)
    return __builtin_amdgcn_exp2f(x);
#else
    return exp2f(x);
#endif
}
__device__ __forceinline__ float fast_rcp(float x) {
#if __has_builtin(__builtin_amdgcn_rcpf)
    return __builtin_amdgcn_rcpf(x);
#else
    return 1.0f / x;
#endif
}

// Each block = (chunk s, batch tile, h half). 1024 blocks x 256 threads =
// 4 blocks/CU, 16 waves/CU (4 waves/SIMD). Lane <-> h column, 8 batches
// register-blocked per lane with an explicit r[8] ILP array. Partials
// combined via f32 atomics into the f32 workspace.
__global__ __launch_bounds__(256, 4) void ltc_accum(
    const float* __restrict__ inputs,   // NB x NI
    const float* __restrict__ state,    // NB x NH
    const float* __restrict__ smu, const float* __restrict__ ssg,
    const float* __restrict__ sW,  const float* __restrict__ ser,
    const float* __restrict__ imu, const float* __restrict__ isg,
    const float* __restrict__ iW,  const float* __restrict__ ier,
    float* __restrict__ wsNum, float* __restrict__ wsDen)
{
    __shared__ float xs[CHUNK][TB];   // inputs chunk, [row][batch]
    __shared__ float ss[CHUNK][TB];   // state  chunk, [row][batch]

    const int bi    = blockIdx.x;
    const int s     = bi & (NS - 1);          // 16 chunks
    const int btile = (bi >> 4) & (NT - 1);   // 32 batch tiles
    const int hhalf = bi >> 9;                // 2 h halves
    const int b0 = btile * TB;
    const int h  = hhalf * HBLK + threadIdx.x;
    const int r0 = s * CHUNK;

    // Stage x/state chunk to LDS, [row][batch] layout. CHUNK*TB == 256.
    {
        const int k  = threadIdx.x;
        const int ii = k >> 3, bb = k & (TB - 1);
        xs[ii][bb] = inputs[(b0 + bb) * NI + r0 + ii];
        ss[ii][bb] = state [(b0 + bb) * NH + r0 + ii];
    }
    __syncthreads();

    float num[TB], den[TB];
#pragma unroll
    for (int bb = 0; bb < TB; ++bb) { num[bb] = 0.f; den[bb] = 0.f; }

    const float LOG2E = 1.44269504088896340736f;

    // sigmoid((x-mu)*sig) = 1/(1+exp2(c - x*a)), a = sig*log2e, c = mu*a
#pragma unroll 2
    for (int ii = 0; ii < CHUNK; ++ii) {
        const int p = (r0 + ii) * NH + h;          // coalesced across lanes
        const float mu = smu[p];
        const float a  = ssg[p] * LOG2E;
        const float W  = sW[p];
        const float We = W * ser[p];
        const float c  = mu * a;
        float r[TB];                               // 8 independent chains
#pragma unroll
        for (int bb = 0; bb < TB; ++bb)
            r[bb] = fast_rcp(1.0f + fast_exp2(c - xs[ii][bb] * a));
#pragma unroll
        for (int bb = 0; bb < TB; ++bb) {
            den[bb] += W  * r[bb];
            num[bb] += We * r[bb];
        }
    }
#pragma unroll 2
    for (int ii = 0; ii < CHUNK; ++ii) {
        const int p = (r0 + ii) * NH + h;
        const float mu = imu[p];
        const float a  = isg[p] * LOG2E;
        const float W  = iW[p];
        const float We = W * ier[p];
        const float c  = mu * a;
        float r[TB];
#pragma unroll
        for (int bb = 0; bb < TB; ++bb)
            r[bb] = fast_rcp(1.0f + fast_exp2(c - ss[ii][bb] * a));
#pragma unroll
        for (int bb = 0; bb < TB; ++bb) {
            den[bb] += W  * r[bb];
            num[bb] += We * r[bb];
        }
    }

#pragma unroll
    for (int bb = 0; bb < TB; ++bb) {
        unsafeAtomicAdd(&wsNum[(b0 + bb) * NH + h], num[bb]);  // global_atomic_add_f32
        unsafeAtomicAdd(&wsDen[(b0 + bb) * NH + h], den[bb]);
    }
}

// Epilogue: one thread per (b,h). Cheap relative to accumulation.
__global__ __launch_bounds__(256) void ltc_epilogue(
    const float* __restrict__ state,
    const float* __restrict__ vleak, const float* __restrict__ gleak,
    const float* __restrict__ cm,
    const float* __restrict__ wsNum, const float* __restrict__ wsDen,
    float* __restrict__ out)
{
    const int t = blockIdx.x * 256 + threadIdx.x;  // < NB*NH
    const int h = t & (NH - 1);
    const float st = state[t];
    const float gl = gleak[h];
    const float vl = vleak[h];
    const float c  = cm[h];
    const float wnum = wsNum[t];
    const float wden = wsDen[t];
    const float eps = 1e-8f;
    const float G = gl + wden;
    const float tau = c / (G + eps);
    const float numerator = c * st + gl * vl + wnum;
    const float denominator = c + G;
    const float v_inf = numerator / (denominator + eps);
    const float next = v_inf + (st - v_inf) * expf(-0.1f / (tau + eps));
    out[t] = tanhf(next);
}

extern "C" void kernel_launch(void* const* d_in, const int* in_sizes, int n_in,
                              void* d_out, int out_size, void* d_ws, size_t ws_size,
                              hipStream_t stream) {
    const float* inputs = (const float*)d_in[0];
    const float* state  = (const float*)d_in[1];
    const float* smu    = (const float*)d_in[2];
    const float* ssg    = (const float*)d_in[3];
    const float* sW     = (const float*)d_in[4];
    const float* ser    = (const float*)d_in[5];
    const float* imu    = (const float*)d_in[6];
    const float* isg    = (const float*)d_in[7];
    const float* iW     = (const float*)d_in[8];
    const float* ier    = (const float*)d_in[9];
    const float* vleak  = (const float*)d_in[10];
    const float* gleak  = (const float*)d_in[11];
    const float* cm     = (const float*)d_in[12];

    float* wsNum = (float*)d_ws;
    float* wsDen = wsNum + NB * NH;

    // ws is re-poisoned (0xAA) before every timed launch -> zero it ourselves.
    hipMemsetAsync(d_ws, 0, 2ull * NB * NH * sizeof(float), stream);

    ltc_accum<<<dim3(NS * NT * 2), dim3(256), 0, stream>>>(
        inputs, state, smu, ssg, sW, ser, imu, isg, iW, ier, wsNum, wsDen);
    ltc_epilogue<<<dim3(NB * NH / 256), dim3(256), 0, stream>>>(
        state, vleak, gleak, cm, wsNum, wsDen, (float*)d_out);
}

// Round 5
// 122.791 us; speedup vs baseline: 1.1599x; 1.0118x over previous
//
#include <hip/hip_runtime.h>
#include <stdint.h>

// Problem: LTCCell  B=256, I=512, H=512. ALL tensors float32, output float32.
// R3: accum 68us, VGPR=36, occ 20%, VALUBusy 35% -> latency-bound.
// R4: TB=8 + r[8] ILP + 4 waves/SIMD -> accum 48us, VALUBusy 58%, occ 29%.
//     Busy-time 27.5us vs ~20.5us issue floor -> still residency-limited.
// R5: fold side (sensory/inter) into the split index (NI==NH==512 -> one
//     code path, pointer-selected). 32 splits x 32 btiles x 2 hhalves =
//     2048 blocks = 8 blocks/CU = 8 waves/SIMD. TB stays 8 (param reuse
//     unchanged). Atomics double (accepted: +16MB overlapped writes).
constexpr int NB = 256;
constexpr int NI = 512;
constexpr int NH = 512;

constexpr int TB    = 8;    // batches register-blocked per lane
constexpr int NT    = 32;   // batch tiles: 256/8
constexpr int CHUNK = 32;   // reduction rows per block
constexpr int NSPL  = 32;   // splits: 16 sensory chunks + 16 inter chunks
constexpr int HBLK  = 256;  // h columns per block (== blockDim.x)

__device__ __forceinline__ float fast_exp2(float x) {
#if __has_builtin(__builtin_amdgcn_exp2f)
    return __builtin_amdgcn_exp2f(x);
#else
    return exp2f(x);
#endif
}
__device__ __forceinline__ float fast_rcp(float x) {
#if __has_builtin(__builtin_amdgcn_rcpf)
    return __builtin_amdgcn_rcpf(x);
#else
    return 1.0f / x;
#endif
}

// Each block = (split sigma, batch tile, h half). 2048 blocks x 256 thr =
// 8 blocks/CU = 8 waves/SIMD. Lane <-> h column, 8 batches register-blocked
// per lane (r[8] ILP array). Partials combined via f32 atomics.
__global__ __launch_bounds__(256, 8) void ltc_accum(
    const float* __restrict__ inputs,   // NB x NI
    const float* __restrict__ state,    // NB x NH
    const float* __restrict__ smu, const float* __restrict__ ssg,
    const float* __restrict__ sW,  const float* __restrict__ ser,
    const float* __restrict__ imu, const float* __restrict__ isg,
    const float* __restrict__ iW,  const float* __restrict__ ier,
    float* __restrict__ wsNum, float* __restrict__ wsDen)
{
    __shared__ float xs[CHUNK][TB];   // x/state chunk, [row][batch]

    const int bi    = blockIdx.x;
    const int sigma = bi & (NSPL - 1);          // 32 splits
    const int btile = (bi >> 5) & (NT - 1);     // 32 batch tiles
    const int hhalf = bi >> 10;                 // 2 h halves
    const int b0 = btile * TB;
    const int h  = hhalf * HBLK + threadIdx.x;

    const bool sens = sigma < 16;
    const int  r0   = (sens ? sigma : sigma - 16) * CHUNK;

    // Side-selected pointers (block-uniform -> scalar select, no divergence).
    const float* __restrict__ src  = sens ? inputs : state;   // NB x 512
    const float* __restrict__ Pmu  = sens ? smu : imu;
    const float* __restrict__ Psg  = sens ? ssg : isg;
    const float* __restrict__ PW   = sens ? sW  : iW;
    const float* __restrict__ Per  = sens ? ser : ier;

    // Stage x/state chunk to LDS, [row][batch] layout. CHUNK*TB == 256.
    {
        const int ii = threadIdx.x >> 3, bb = threadIdx.x & (TB - 1);
        xs[ii][bb] = src[(b0 + bb) * 512 + r0 + ii];
    }
    __syncthreads();

    float num[TB], den[TB];
#pragma unroll
    for (int bb = 0; bb < TB; ++bb) { num[bb] = 0.f; den[bb] = 0.f; }

    const float LOG2E = 1.44269504088896340736f;

    // sigmoid((x-mu)*sig) = 1/(1+exp2(c - x*a)), a = sig*log2e, c = mu*a
#pragma unroll 2
    for (int ii = 0; ii < CHUNK; ++ii) {
        const int p = (r0 + ii) * NH + h;          // coalesced across lanes
        const float mu = Pmu[p];
        const float a  = Psg[p] * LOG2E;
        const float W  = PW[p];
        const float We = W * Per[p];
        const float c  = mu * a;
        float r[TB];                               // 8 independent chains
#pragma unroll
        for (int bb = 0; bb < TB; ++bb)
            r[bb] = fast_rcp(1.0f + fast_exp2(c - xs[ii][bb] * a));
#pragma unroll
        for (int bb = 0; bb < TB; ++bb) {
            den[bb] += W  * r[bb];
            num[bb] += We * r[bb];
        }
    }

#pragma unroll
    for (int bb = 0; bb < TB; ++bb) {
        unsafeAtomicAdd(&wsNum[(b0 + bb) * NH + h], num[bb]);  // global_atomic_add_f32
        unsafeAtomicAdd(&wsDen[(b0 + bb) * NH + h], den[bb]);
    }
}

// Epilogue: one thread per (b,h). Cheap relative to accumulation.
__global__ __launch_bounds__(256) void ltc_epilogue(
    const float* __restrict__ state,
    const float* __restrict__ vleak, const float* __restrict__ gleak,
    const float* __restrict__ cm,
    const float* __restrict__ wsNum, const float* __restrict__ wsDen,
    float* __restrict__ out)
{
    const int t = blockIdx.x * 256 + threadIdx.x;  // < NB*NH
    const int h = t & (NH - 1);
    const float st = state[t];
    const float gl = gleak[h];
    const float vl = vleak[h];
    const float c  = cm[h];
    const float wnum = wsNum[t];
    const float wden = wsDen[t];
    const float eps = 1e-8f;
    const float G = gl + wden;
    const float tau = c / (G + eps);
    const float numerator = c * st + gl * vl + wnum;
    const float denominator = c + G;
    const float v_inf = numerator / (denominator + eps);
    const float next = v_inf + (st - v_inf) * expf(-0.1f / (tau + eps));
    out[t] = tanhf(next);
}

extern "C" void kernel_launch(void* const* d_in, const int* in_sizes, int n_in,
                              void* d_out, int out_size, void* d_ws, size_t ws_size,
                              hipStream_t stream) {
    const float* inputs = (const float*)d_in[0];
    const float* state  = (const float*)d_in[1];
    const float* smu    = (const float*)d_in[2];
    const float* ssg    = (const float*)d_in[3];
    const float* sW     = (const float*)d_in[4];
    const float* ser    = (const float*)d_in[5];
    const float* imu    = (const float*)d_in[6];
    const float* isg    = (const float*)d_in[7];
    const float* iW     = (const float*)d_in[8];
    const float* ier    = (const float*)d_in[9];
    const float* vleak  = (const float*)d_in[10];
    const float* gleak  = (const float*)d_in[11];
    const float* cm     = (const float*)d_in[12];

    float* wsNum = (float*)d_ws;
    float* wsDen = wsNum + NB * NH;

    // ws is re-poisoned (0xAA) before every timed launch -> zero it ourselves.
    hipMemsetAsync(d_ws, 0, 2ull * NB * NH * sizeof(float), stream);

    ltc_accum<<<dim3(NSPL * NT * 2), dim3(256), 0, stream>>>(
        inputs, state, smu, ssg, sW, ser, imu, isg, iW, ier, wsNum, wsDen);
    ltc_epilogue<<<dim3(NB * NH / 256), dim3(256), 0, stream>>>(
        state, vleak, gleak, cm, wsNum, wsDen, (float*)d_out);
}